// Round 13
// baseline (257.791 us; speedup 1.0000x reference)
//
#include <hip/hip_runtime.h>

#define NN 50000
#define NE 800000
#define FIN 128
#define HD 64
#define SL 3
#define GBM 782    // ceil(NN/64) row-tiles for MFMA kernels
#define NBIN 196   // ceil(NN/256) dst bins
#define BSH 8      // 256 nodes per bin
#define CAP 8064   // per-bin tedge capacity (mean 4082, ~62 sigma headroom)
#define SCB 25000  // scatter blocks: 2 halves x 12500

typedef __attribute__((ext_vector_type(8))) short bf16x8;
typedef __attribute__((ext_vector_type(4))) float f32x4;
#define MFMA(A, B, C) __builtin_amdgcn_mfma_f32_16x16x32_bf16(A, B, C, 0, 0, 0)

// ---------------- bf16 pack helpers (RNE) ----------------

__device__ __forceinline__ unsigned int bfr(float x) {
    unsigned int u = __float_as_uint(x);
    return (u + 0x7fffu + ((u >> 16) & 1u)) >> 16;
}
__device__ __forceinline__ unsigned int bf2(float lo, float hi) {
    return bfr(lo) | (bfr(hi) << 16);
}

// ---------------- CSR build ----------------

// replaces hipMemsetAsync (captured fillBufferAligned costs ~47 us/replay)
__global__ void zero_k(int* __restrict__ g) {
    if (threadIdx.x < NBIN) g[threadIdx.x] = 0;
}

// partition edges into per-bin STRIDED runs (tedge[b*CAP + ...]); gcur counts.
// packed: src (16b) | (dst & 255) << 16
__global__ __launch_bounds__(256) void binpass_k(const int* __restrict__ src,
                                                 const int* __restrict__ dst,
                                                 const float* __restrict__ attr,
                                                 int* __restrict__ gcur,
                                                 int2* __restrict__ tedge) {
    __shared__ int cnt_lds[256], runbase[256], lcur[256];
    int t = threadIdx.x;
    cnt_lds[t] = 0;
    lcur[t] = 0;
    __syncthreads();
    int base = blockIdx.x * 4096;
    for (int i = t; i < 4096; i += 256) {
        int e = base + i;
        if (e < NE) atomicAdd(&cnt_lds[dst[e] >> BSH], 1);
    }
    __syncthreads();
    if (t < NBIN && cnt_lds[t]) runbase[t] = atomicAdd(&gcur[t], cnt_lds[t]);
    __syncthreads();
    for (int i = t; i < 4096; i += 256) {
        int e = base + i;
        if (e < NE) {
            int d = dst[e];
            int b = d >> BSH;
            int r = atomicAdd(&lcur[b], 1);
            tedge[(size_t)b * CAP + runbase[b] + r] =
                make_int2(src[e] | ((d & 255) << 16), __float_as_int(attr[e]));
        }
    }
}

// blocks [0,NBIN): per-bin counting sort; blocks [NBIN,NBIN+128): weight prep.
__global__ __launch_bounds__(256) void sortprep_k(const int* __restrict__ gcur,
                                                  const int2* __restrict__ tedge,
                                                  int2* __restrict__ cedge,
                                                  int* __restrict__ off,
                                                  const float* __restrict__ W1,
                                                  const float* __restrict__ W2,
                                                  const float* __restrict__ linW,
                                                  short* __restrict__ prep) {
    int t = threadIdx.x;
    if (blockIdx.x >= NBIN) {
        int i = (blockIdx.x - NBIN) * 256 + t;
        if (i < 24576) {
            int mat = i >> 12;
            int o = i & 4095;
            int j = o & 7, l = (o >> 3) & 63, s = (o >> 9) & 1, tt = o >> 10;
            int k = 32 * s + 8 * (l >> 4) + j;
            int n = 16 * tt + (l & 15);
            const float* Wsrc = (mat & 1) ? W2 : W1;
            prep[i] = (short)bfr(Wsrc[(mat >> 1) * 4096 + k * 64 + n]);
        } else if (i < 32768) {
            int o = i - 24576;
            int j = o & 7, l = (o >> 3) & 63, s = (o >> 9) & 3, tt = o >> 11;
            int k = 32 * s + 8 * (l >> 4) + j;
            int n = 16 * tt + (l & 15);
            prep[i] = (short)bfr(linW[k * 64 + n]);
        }
        return;
    }
    __shared__ int sh[256], cnt[256], lofs[256], lcur[256];
    int b = blockIdx.x;
    int v = (t < NBIN) ? gcur[t] : 0;
    sh[t] = v;
    __syncthreads();
    for (int d = 1; d < 256; d <<= 1) {
        int u = (t >= d) ? sh[t - d] : 0;
        __syncthreads();
        sh[t] += u;
        __syncthreads();
    }
    int s = (b == 0) ? 0 : sh[b - 1];       // binoff[b]
    int n_in_bin = sh[b] - s;
    if (b == NBIN - 1 && t == 0) off[NN] = sh[NBIN - 1];  // == NE

    const int2* tb = tedge + (size_t)b * CAP;
    cnt[t] = 0;
    __syncthreads();
    for (int i = t; i < n_in_bin; i += 256)
        atomicAdd(&cnt[((unsigned)tb[i].x >> 16) & 255], 1);
    __syncthreads();
    int cv = cnt[t];
    lofs[t] = cv;
    __syncthreads();
    for (int d = 1; d < 256; d <<= 1) {
        int u = (t >= d) ? lofs[t - d] : 0;
        __syncthreads();
        lofs[t] += u;
        __syncthreads();
    }
    int ex = lofs[t] - cv;  // exclusive prefix within bin
    int node = (b << BSH) + t;
    if (node < NN) off[node] = s + ex;
    lcur[t] = ex;
    __syncthreads();
    for (int i = t; i < n_in_bin; i += 256) {
        int2 ed = tb[i];
        int dl = ((unsigned)ed.x >> 16) & 255;
        int p = s + atomicAdd(&lcur[dl], 1);
        cedge[p] = make_int2(ed.x & 0xffff, ed.y);
    }
}

// ---------------- scatter: feature-split halves, wave per (node, half) ----------------

__global__ __launch_bounds__(256) void scatter_k(const uint4* __restrict__ hbL,
                                                 const uint4* __restrict__ hbH,
                                                 const int* __restrict__ off,
                                                 const int2* __restrict__ cedge,
                                                 uint4* __restrict__ mbL,
                                                 uint4* __restrict__ mbH) {
    int gid = blockIdx.x * 4 + (int)(threadIdx.x >> 6);
    int half = gid >= NN;
    int w = half ? gid - NN : gid;
    const uint4* hb4 = half ? hbH : hbL;
    uint4* mb4 = half ? mbH : mbL;
    int lane = threadIdx.x & 63;
    int g = lane >> 2;   // edge slot 0..15
    int f = lane & 3;    // uint4 chunk within 16-uint half-row
    int s = off[w], e = off[w + 1];
    float a0 = 0.f, a1 = 0.f, a2 = 0.f, a3 = 0.f;
    float a4 = 0.f, a5 = 0.f, a6 = 0.f, a7 = 0.f;
    for (int i = s + g; i < e; i += 16) {
        int2 ed = cedge[i];
        uint4 hv = hb4[(size_t)ed.x * 4 + f];
        float a = __int_as_float(ed.y);
        a0 += a * __uint_as_float(hv.x << 16);
        a1 += a * __uint_as_float(hv.x & 0xffff0000u);
        a2 += a * __uint_as_float(hv.y << 16);
        a3 += a * __uint_as_float(hv.y & 0xffff0000u);
        a4 += a * __uint_as_float(hv.z << 16);
        a5 += a * __uint_as_float(hv.z & 0xffff0000u);
        a6 += a * __uint_as_float(hv.w << 16);
        a7 += a * __uint_as_float(hv.w & 0xffff0000u);
    }
#pragma unroll
    for (int msk = 4; msk <= 32; msk <<= 1) {
        a0 += __shfl_xor(a0, msk);
        a1 += __shfl_xor(a1, msk);
        a2 += __shfl_xor(a2, msk);
        a3 += __shfl_xor(a3, msk);
        a4 += __shfl_xor(a4, msk);
        a5 += __shfl_xor(a5, msk);
        a6 += __shfl_xor(a6, msk);
        a7 += __shfl_xor(a7, msk);
    }
    if (g == 0) {
        uint4 o;
        o.x = bf2(a0, a1);
        o.y = bf2(a2, a3);
        o.z = bf2(a4, a5);
        o.w = bf2(a6, a7);
        mb4[(size_t)w * 4 + f] = o;
    }
}

// ---------------- MFMA conv core (one weight set) ----------------

__device__ __forceinline__ void conv_core(bf16x8 a0, bf16x8 a1,
                                          const bf16x8* __restrict__ w1f,
                                          const float* __restrict__ b1,
                                          const bf16x8* __restrict__ w2f,
                                          short* tw, int c, int q, int l,
                                          f32x4 oc[4]) {
    f32x4 acc[4];
#pragma unroll
    for (int t = 0; t < 4; t++) acc[t] = (f32x4){0.f, 0.f, 0.f, 0.f};
#pragma unroll
    for (int t = 0; t < 4; t++) {
        acc[t] = MFMA(a0, w1f[(t * 2 + 0) * 64 + l], acc[t]);
        acc[t] = MFMA(a1, w1f[(t * 2 + 1) * 64 + l], acc[t]);
    }
#pragma unroll
    for (int t = 0; t < 4; t++) {
        float bb = b1[16 * t + c];
#pragma unroll
        for (int rg = 0; rg < 4; rg++) {
            float v = fmaxf(acc[t][rg] + bb, 0.f);
            tw[(4 * q + rg) * 72 + 16 * t + c] = (short)bfr(v);
        }
    }
    __syncthreads();
    bf16x8 ta0 = *(const bf16x8*)&tw[c * 72 + 8 * q];
    bf16x8 ta1 = *(const bf16x8*)&tw[c * 72 + 32 + 8 * q];
#pragma unroll
    for (int t = 0; t < 4; t++) oc[t] = (f32x4){0.f, 0.f, 0.f, 0.f};
#pragma unroll
    for (int t = 0; t < 4; t++) {
        oc[t] = MFMA(ta0, w2f[(t * 2 + 0) * 64 + l], oc[t]);
        oc[t] = MFMA(ta1, w2f[(t * 2 + 1) * 64 + l], oc[t]);
    }
}

// ---------------- A-fragment load from split mb ----------------

__device__ __forceinline__ void load_afrag(const uint4* __restrict__ mbL,
                                           const uint4* __restrict__ mbH,
                                           int ar, int q, bf16x8& a0, bf16x8& a1) {
    uint4 v0 = make_uint4(0, 0, 0, 0), v1 = v0;
    if (ar < NN) {
        v0 = mbL[(size_t)ar * 4 + q];
        v1 = mbH[(size_t)ar * 4 + q];
    }
    a0 = *(bf16x8*)&v0;
    a1 = *(bf16x8*)&v1;
}

// ---------------- bf16 WB to split hb ----------------
// CALLER MUST GUARD row < NN (row is uniform across the 16 c-lanes and the
// shfl partner c^1 shares the same row, so the guard never splits a pair).

__device__ __forceinline__ void wb_hb(unsigned int* __restrict__ hbL,
                                      unsigned int* __restrict__ hbH,
                                      int row, int t, int c, float v) {
    float o = __shfl_xor(v, 1);
    if ((c & 1) == 0) {
        unsigned int* hx = (t < 2) ? hbL : hbH;
        hx[(size_t)row * 16 + 8 * (t & 1) + (c >> 1)] = bf2(v, o);
    }
}

// ---------------- single conv: out = [hprev +] relu(m@W1+b1)@W2+b2 ----------------

template <bool ADD, bool WB>
__global__ __launch_bounds__(256) void convm_k(const uint4* __restrict__ mbL,
                                               const uint4* __restrict__ mbH,
                                               const short* __restrict__ w1p,
                                               const float* __restrict__ b1,
                                               const short* __restrict__ w2p,
                                               const float* __restrict__ b2,
                                               const float* __restrict__ hprev,
                                               float* __restrict__ out,
                                               unsigned int* __restrict__ hbL,
                                               unsigned int* __restrict__ hbH) {
    __shared__ short tls[4][16 * 72];
    int wv = threadIdx.x >> 6, l = threadIdx.x & 63;
    int c = l & 15, q = l >> 4;
    int rbase = blockIdx.x * 64 + wv * 16;

    bf16x8 a0, a1;
    load_afrag(mbL, mbH, rbase + c, q, a0, a1);

    f32x4 oc[4];
    conv_core(a0, a1, (const bf16x8*)w1p, b1, (const bf16x8*)w2p, tls[wv], c, q, l, oc);

#pragma unroll
    for (int t = 0; t < 4; t++) {
        float bb = b2[16 * t + c];
#pragma unroll
        for (int rg = 0; rg < 4; rg++) {
            int row = rbase + 4 * q + rg;
            if (row < NN) {
                float v = oc[t][rg] + bb;
                if constexpr (ADD) v += hprev[(size_t)row * 64 + 16 * t + c];
                out[(size_t)row * 64 + 16 * t + c] = v;
                if constexpr (WB) wb_hb(hbL, hbH, row, t, c, v);
            }
        }
    }
}

// ---------------- dual conv: outa = conv_a(m); outb = hprev + conv_b(m) (+bf16 WB) ----------------

__global__ __launch_bounds__(256) void conv2_k(const uint4* __restrict__ mbL,
                                               const uint4* __restrict__ mbH,
                                               const short* __restrict__ wa1,
                                               const float* __restrict__ ba1,
                                               const short* __restrict__ wa2,
                                               const float* __restrict__ ba2,
                                               const short* __restrict__ wb1,
                                               const float* __restrict__ bb1,
                                               const short* __restrict__ wb2,
                                               const float* __restrict__ bb2,
                                               const float* __restrict__ hprev,
                                               float* __restrict__ outa,
                                               float* __restrict__ outb,
                                               unsigned int* __restrict__ hbL,
                                               unsigned int* __restrict__ hbH) {
    __shared__ short tls[4][16 * 72];
    int wv = threadIdx.x >> 6, l = threadIdx.x & 63;
    int c = l & 15, q = l >> 4;
    int rbase = blockIdx.x * 64 + wv * 16;

    bf16x8 a0, a1;
    load_afrag(mbL, mbH, rbase + c, q, a0, a1);

    f32x4 oc[4];
    conv_core(a0, a1, (const bf16x8*)wa1, ba1, (const bf16x8*)wa2, tls[wv], c, q, l, oc);
#pragma unroll
    for (int t = 0; t < 4; t++) {
        float bb = ba2[16 * t + c];
#pragma unroll
        for (int rg = 0; rg < 4; rg++) {
            int row = rbase + 4 * q + rg;
            if (row < NN)
                outa[(size_t)row * 64 + 16 * t + c] = oc[t][rg] + bb;
        }
    }
    __syncthreads();  // tls reuse

    conv_core(a0, a1, (const bf16x8*)wb1, bb1, (const bf16x8*)wb2, tls[wv], c, q, l, oc);
#pragma unroll
    for (int t = 0; t < 4; t++) {
        float bb = bb2[16 * t + c];
#pragma unroll
        for (int rg = 0; rg < 4; rg++) {
            int row = rbase + 4 * q + rg;
            if (row < NN) {   // guard BOTH out write and hb WB (row races otherwise)
                float v = oc[t][rg] + bb + hprev[(size_t)row * 64 + 16 * t + c];
                outb[(size_t)row * 64 + 16 * t + c] = v;
                wb_hb(hbL, hbH, row, t, c, v);
            }
        }
    }
}

// ---------------- MFMA input linear: h0 = x @ lin_W + lin_b (+ bf16 copy) ----------------

__global__ __launch_bounds__(256) void linm_k(const float* __restrict__ x,
                                              const short* __restrict__ wp,
                                              const float* __restrict__ b,
                                              float* __restrict__ h0,
                                              unsigned int* __restrict__ hbL,
                                              unsigned int* __restrict__ hbH) {
    int wv = threadIdx.x >> 6, l = threadIdx.x & 63;
    int c = l & 15, q = l >> 4;
    int rbase = blockIdx.x * 64 + wv * 16;
    int ar = rbase + c;
    bool aok = ar < NN;

    bf16x8 af[4];
#pragma unroll
    for (int s = 0; s < 4; s++) {
        float4 p0 = make_float4(0, 0, 0, 0), p1 = p0;
        if (aok) {
            const float4* xp = (const float4*)(x + (size_t)ar * FIN + 32 * s + 8 * q);
            p0 = xp[0];
            p1 = xp[1];
        }
        bf16x8 t;
        t[0] = (short)bfr(p0.x); t[1] = (short)bfr(p0.y);
        t[2] = (short)bfr(p0.z); t[3] = (short)bfr(p0.w);
        t[4] = (short)bfr(p1.x); t[5] = (short)bfr(p1.y);
        t[6] = (short)bfr(p1.z); t[7] = (short)bfr(p1.w);
        af[s] = t;
    }

    const bf16x8* wf = (const bf16x8*)wp;
    f32x4 acc[4];
#pragma unroll
    for (int t = 0; t < 4; t++) acc[t] = (f32x4){0.f, 0.f, 0.f, 0.f};
#pragma unroll
    for (int t = 0; t < 4; t++)
#pragma unroll
        for (int s = 0; s < 4; s++)
            acc[t] = MFMA(af[s], wf[(t * 4 + s) * 64 + l], acc[t]);

#pragma unroll
    for (int t = 0; t < 4; t++) {
        float bb = b[16 * t + c];
#pragma unroll
        for (int rg = 0; rg < 4; rg++) {
            int row = rbase + 4 * q + rg;
            if (row < NN) {   // guard BOTH h0 write and hb WB
                float v = acc[t][rg] + bb;
                h0[(size_t)row * 64 + 16 * t + c] = v;
                wb_hb(hbL, hbH, row, t, c, v);
            }
        }
    }
}

// ---------------- launch ----------------

extern "C" void kernel_launch(void* const* d_in, const int* in_sizes, int n_in,
                              void* d_out, int out_size, void* d_ws, size_t ws_size,
                              hipStream_t stream) {
    (void)in_sizes; (void)n_in; (void)out_size; (void)ws_size;

    const float* x    = (const float*)d_in[0];
    const int*   ei   = (const int*)d_in[1];
    const float* attr = (const float*)d_in[2];
    const float* linW = (const float*)d_in[3];
    const float* linb = (const float*)d_in[4];
    const float* W1   = (const float*)d_in[5];
    const float* b1   = (const float*)d_in[6];
    const float* W2   = (const float*)d_in[7];
    const float* b2   = (const float*)d_in[8];
    float* out = (float*)d_out;

    // workspace (16B alignment at each boundary)
    float*        h0     = (float*)d_ws;                          // NN*64 f32 (12.8MB)
    unsigned int* mbL    = (unsigned int*)(h0 + (size_t)NN * HD); // NN*16 (bf16 m, feats 0-31)
    unsigned int* mbH    = mbL + (size_t)NN * 16;                 // NN*16 (feats 32-63)
    unsigned int* hbL    = mbH + (size_t)NN * 16;                 // NN*16 (bf16 h, feats 0-31)
    unsigned int* hbH    = hbL + (size_t)NN * 16;                 // NN*16 (feats 32-63)
    int2*         cedge  = (int2*)(hbH + (size_t)NN * 16);        // NE (node-sorted)
    short*        prep   = (short*)(cedge + NE);                  // 32768 shorts
    int*          off    = (int*)(prep + 32768);                  // NN+1
    int*          gcur   = off + NN + 1;                          // 256 (bin counts)
    int2*         tedge  = (int2*)h0;  // ALIAS: 196*CAP*8B = 12.64MB <= 12.8MB; h0 dead until linm_k

    const int* src = ei;
    const int* dst = ei + NE;

    float* scats = out;
    float* outs  = out + (size_t)SL * NN * HD;

    const size_t NH = (size_t)NN * HD;

    const short* w1p0 = prep;            // layer i: prep + i*8192
    const short* w2p0 = prep + 4096;
    const short* linp = prep + 24576;

    // CSR build: zero -> strided binpass (counts in gcur) -> fused sort+wprep
    zero_k<<<1, 256, 0, stream>>>(gcur);
    binpass_k<<<196, 256, 0, stream>>>(src, dst, attr, gcur, tedge);
    sortprep_k<<<NBIN + 128, 256, 0, stream>>>(gcur, tedge, cedge, off,
                                               W1, W2, linW, prep);

    // h0 = x @ lin_W + lin_b (+ bf16 into hbL/hbH)
    linm_k<<<GBM, 256, 0, stream>>>(x, linp, linb, h0, hbL, hbH);

    // layer 0
    scatter_k<<<SCB, 256, 0, stream>>>((const uint4*)hbL, (const uint4*)hbH, off, cedge,
                                       (uint4*)mbL, (uint4*)mbH);
    convm_k<true, true><<<GBM, 256, 0, stream>>>((const uint4*)mbL, (const uint4*)mbH,
                                                 w1p0, b1, w2p0, b2, h0, outs, hbL, hbH);

    // scatter(outs0): scats0 (W0) + outs1 (W1) fused
    scatter_k<<<SCB, 256, 0, stream>>>((const uint4*)hbL, (const uint4*)hbH, off, cedge,
                                       (uint4*)mbL, (uint4*)mbH);
    conv2_k<<<GBM, 256, 0, stream>>>((const uint4*)mbL, (const uint4*)mbH,
                                     w1p0, b1, w2p0, b2,
                                     w1p0 + 8192, b1 + 64, w2p0 + 8192, b2 + 64,
                                     outs, scats, outs + NH, hbL, hbH);

    // scatter(outs1): scats1 (W1) + outs2 (W2) fused
    scatter_k<<<SCB, 256, 0, stream>>>((const uint4*)hbL, (const uint4*)hbH, off, cedge,
                                       (uint4*)mbL, (uint4*)mbH);
    conv2_k<<<GBM, 256, 0, stream>>>((const uint4*)mbL, (const uint4*)mbH,
                                     w1p0 + 8192, b1 + 64, w2p0 + 8192, b2 + 64,
                                     w1p0 + 16384, b1 + 128, w2p0 + 16384, b2 + 128,
                                     outs + NH, scats + NH, outs + 2 * NH, hbL, hbH);

    // scatter(outs2): scats2 (W2)
    scatter_k<<<SCB, 256, 0, stream>>>((const uint4*)hbL, (const uint4*)hbH, off, cedge,
                                       (uint4*)mbL, (uint4*)mbH);
    convm_k<false, false><<<GBM, 256, 0, stream>>>((const uint4*)mbL, (const uint4*)mbH,
                                                   w1p0 + 16384, b1 + 128,
                                                   w2p0 + 16384, b2 + 128,
                                                   nullptr, scats + 2 * NH, nullptr, nullptr);
}

// Round 15
// 213.421 us; speedup vs baseline: 1.2079x; 1.2079x over previous
//
#include <hip/hip_runtime.h>

#define NN 50000
#define NE 800000
#define FIN 128
#define HD 64
#define SL 3
#define GBM 782    // ceil(NN/64) row-tiles for MFMA kernels
#define NBIN 196   // ceil(NN/256) dst bins
#define BSH 8      // 256 nodes per bin
#define CAP 8064   // per-bin tedge capacity (mean 4082, ~62 sigma headroom)

typedef __attribute__((ext_vector_type(8))) short bf16x8;
typedef __attribute__((ext_vector_type(4))) float f32x4;
#define MFMA(A, B, C) __builtin_amdgcn_mfma_f32_16x16x32_bf16(A, B, C, 0, 0, 0)

// ---------------- bf16 pack helpers (RNE) ----------------

__device__ __forceinline__ unsigned int bfr(float x) {
    unsigned int u = __float_as_uint(x);
    return (u + 0x7fffu + ((u >> 16) & 1u)) >> 16;
}
__device__ __forceinline__ unsigned int bf2(float lo, float hi) {
    return bfr(lo) | (bfr(hi) << 16);
}

// ---------------- CSR build ----------------

// replaces hipMemsetAsync (captured fillBufferAligned costs ~47 us/replay)
__global__ void zero_k(int* __restrict__ g) {
    if (threadIdx.x < NBIN) g[threadIdx.x] = 0;
}

// partition edges into per-bin STRIDED runs (tedge[b*CAP + ...]); gcur counts.
// packed: src (16b) | (dst & 255) << 16.  1024 edges/block, 782 blocks.
__global__ __launch_bounds__(256) void binpass_k(const int* __restrict__ src,
                                                 const int* __restrict__ dst,
                                                 const float* __restrict__ attr,
                                                 int* __restrict__ gcur,
                                                 int2* __restrict__ tedge) {
    __shared__ int cnt_lds[256], runbase[256], lcur[256];
    int t = threadIdx.x;
    cnt_lds[t] = 0;
    lcur[t] = 0;
    __syncthreads();
    int base = blockIdx.x * 1024;
    for (int i = t; i < 1024; i += 256) {
        int e = base + i;
        if (e < NE) atomicAdd(&cnt_lds[dst[e] >> BSH], 1);
    }
    __syncthreads();
    if (t < NBIN && cnt_lds[t]) runbase[t] = atomicAdd(&gcur[t], cnt_lds[t]);
    __syncthreads();
    for (int i = t; i < 1024; i += 256) {
        int e = base + i;
        if (e < NE) {
            int d = dst[e];
            int b = d >> BSH;
            int r = atomicAdd(&lcur[b], 1);
            tedge[(size_t)b * CAP + runbase[b] + r] =
                make_int2(src[e] | ((d & 255) << 16), __float_as_int(attr[e]));
        }
    }
}

// blocks [0,NBIN): per-bin counting sort; blocks [NBIN,NBIN+128): weight prep.
__global__ __launch_bounds__(256) void sortprep_k(const int* __restrict__ gcur,
                                                  const int2* __restrict__ tedge,
                                                  int2* __restrict__ cedge,
                                                  int* __restrict__ off,
                                                  const float* __restrict__ W1,
                                                  const float* __restrict__ W2,
                                                  const float* __restrict__ linW,
                                                  short* __restrict__ prep) {
    int t = threadIdx.x;
    if (blockIdx.x >= NBIN) {
        int i = (blockIdx.x - NBIN) * 256 + t;
        if (i < 24576) {
            int mat = i >> 12;
            int o = i & 4095;
            int j = o & 7, l = (o >> 3) & 63, s = (o >> 9) & 1, tt = o >> 10;
            int k = 32 * s + 8 * (l >> 4) + j;
            int n = 16 * tt + (l & 15);
            const float* Wsrc = (mat & 1) ? W2 : W1;
            prep[i] = (short)bfr(Wsrc[(mat >> 1) * 4096 + k * 64 + n]);
        } else if (i < 32768) {
            int o = i - 24576;
            int j = o & 7, l = (o >> 3) & 63, s = (o >> 9) & 3, tt = o >> 11;
            int k = 32 * s + 8 * (l >> 4) + j;
            int n = 16 * tt + (l & 15);
            prep[i] = (short)bfr(linW[k * 64 + n]);
        }
        return;
    }
    __shared__ int sh[256], cnt[256], lofs[256], lcur[256];
    int b = blockIdx.x;
    int v = (t < NBIN) ? gcur[t] : 0;
    sh[t] = v;
    __syncthreads();
    for (int d = 1; d < 256; d <<= 1) {
        int u = (t >= d) ? sh[t - d] : 0;
        __syncthreads();
        sh[t] += u;
        __syncthreads();
    }
    int s = (b == 0) ? 0 : sh[b - 1];       // binoff[b]
    int n_in_bin = sh[b] - s;
    if (b == NBIN - 1 && t == 0) off[NN] = sh[NBIN - 1];  // == NE

    const int2* tb = tedge + (size_t)b * CAP;
    cnt[t] = 0;
    __syncthreads();
    for (int i = t; i < n_in_bin; i += 256)
        atomicAdd(&cnt[((unsigned)tb[i].x >> 16) & 255], 1);
    __syncthreads();
    int cv = cnt[t];
    lofs[t] = cv;
    __syncthreads();
    for (int d = 1; d < 256; d <<= 1) {
        int u = (t >= d) ? lofs[t - d] : 0;
        __syncthreads();
        lofs[t] += u;
        __syncthreads();
    }
    int ex = lofs[t] - cv;  // exclusive prefix within bin
    int node = (b << BSH) + t;
    if (node < NN) off[node] = s + ex;
    lcur[t] = ex;
    __syncthreads();
    for (int i = t; i < n_in_bin; i += 256) {
        int2 ed = tb[i];
        int dl = ((unsigned)ed.x >> 16) & 255;
        int p = s + atomicAdd(&lcur[dl], 1);
        cedge[p] = make_int2(ed.x & 0xffff, ed.y);
    }
}

// ---------------- scatter: mb[n] = bf16( sum attr[e] * hb[src[e]] ) ----------------
// wave per dst node; 8 lanes per edge, shfl-xor tree reduce. No atomics.
// (R11 structure — best measured; R9 fusion and R13 feature-split both regressed.)

__global__ __launch_bounds__(256) void scatter_k(const uint4* __restrict__ hb4,
                                                 const int* __restrict__ off,
                                                 const int2* __restrict__ cedge,
                                                 uint4* __restrict__ mb4) {
    int w    = (blockIdx.x * blockDim.x + threadIdx.x) >> 6;
    int lane = threadIdx.x & 63;
    if (w >= NN) return;
    int g = lane >> 3;
    int f = lane & 7;
    int s = off[w], e = off[w + 1];
    float a0 = 0.f, a1 = 0.f, a2 = 0.f, a3 = 0.f;
    float a4 = 0.f, a5 = 0.f, a6 = 0.f, a7 = 0.f;
    for (int i = s + g; i < e; i += 8) {
        int2 ed = cedge[i];
        uint4 hv = hb4[(size_t)ed.x * 8 + f];
        float a = __int_as_float(ed.y);
        a0 += a * __uint_as_float(hv.x << 16);
        a1 += a * __uint_as_float(hv.x & 0xffff0000u);
        a2 += a * __uint_as_float(hv.y << 16);
        a3 += a * __uint_as_float(hv.y & 0xffff0000u);
        a4 += a * __uint_as_float(hv.z << 16);
        a5 += a * __uint_as_float(hv.z & 0xffff0000u);
        a6 += a * __uint_as_float(hv.w << 16);
        a7 += a * __uint_as_float(hv.w & 0xffff0000u);
    }
#pragma unroll
    for (int msk = 8; msk <= 32; msk <<= 1) {
        a0 += __shfl_xor(a0, msk);
        a1 += __shfl_xor(a1, msk);
        a2 += __shfl_xor(a2, msk);
        a3 += __shfl_xor(a3, msk);
        a4 += __shfl_xor(a4, msk);
        a5 += __shfl_xor(a5, msk);
        a6 += __shfl_xor(a6, msk);
        a7 += __shfl_xor(a7, msk);
    }
    if (g == 0) {
        uint4 o;
        o.x = bf2(a0, a1);
        o.y = bf2(a2, a3);
        o.z = bf2(a4, a5);
        o.w = bf2(a6, a7);
        mb4[(size_t)w * 8 + f] = o;
    }
}

// ---------------- MFMA conv core (one weight set) ----------------

__device__ __forceinline__ void conv_core(bf16x8 a0, bf16x8 a1,
                                          const bf16x8* __restrict__ w1f,
                                          const float* __restrict__ b1,
                                          const bf16x8* __restrict__ w2f,
                                          short* tw, int c, int q, int l,
                                          f32x4 oc[4]) {
    f32x4 acc[4];
#pragma unroll
    for (int t = 0; t < 4; t++) acc[t] = (f32x4){0.f, 0.f, 0.f, 0.f};
#pragma unroll
    for (int t = 0; t < 4; t++) {
        acc[t] = MFMA(a0, w1f[(t * 2 + 0) * 64 + l], acc[t]);
        acc[t] = MFMA(a1, w1f[(t * 2 + 1) * 64 + l], acc[t]);
    }
#pragma unroll
    for (int t = 0; t < 4; t++) {
        float bb = b1[16 * t + c];
#pragma unroll
        for (int rg = 0; rg < 4; rg++) {
            float v = fmaxf(acc[t][rg] + bb, 0.f);
            tw[(4 * q + rg) * 72 + 16 * t + c] = (short)bfr(v);
        }
    }
    __syncthreads();
    bf16x8 ta0 = *(const bf16x8*)&tw[c * 72 + 8 * q];
    bf16x8 ta1 = *(const bf16x8*)&tw[c * 72 + 32 + 8 * q];
#pragma unroll
    for (int t = 0; t < 4; t++) oc[t] = (f32x4){0.f, 0.f, 0.f, 0.f};
#pragma unroll
    for (int t = 0; t < 4; t++) {
        oc[t] = MFMA(ta0, w2f[(t * 2 + 0) * 64 + l], oc[t]);
        oc[t] = MFMA(ta1, w2f[(t * 2 + 1) * 64 + l], oc[t]);
    }
}

// ---------------- single conv: out = [hprev +] relu(m@W1+b1)@W2+b2 ----------------

template <bool ADD, bool WB>
__global__ __launch_bounds__(256) void convm_k(const unsigned int* __restrict__ mb,
                                               const short* __restrict__ w1p,
                                               const float* __restrict__ b1,
                                               const short* __restrict__ w2p,
                                               const float* __restrict__ b2,
                                               const float* __restrict__ hprev,
                                               float* __restrict__ out,
                                               unsigned int* __restrict__ hb) {
    __shared__ short tls[4][16 * 72];
    int wv = threadIdx.x >> 6, l = threadIdx.x & 63;
    int c = l & 15, q = l >> 4;
    int rbase = blockIdx.x * 64 + wv * 16;

    int ar = rbase + c;
    bool aok = ar < NN;
    uint4 v0 = make_uint4(0, 0, 0, 0), v1 = v0;
    if (aok) {
        const uint4* mp = (const uint4*)(mb + (size_t)ar * 32);
        v0 = mp[q];
        v1 = mp[4 + q];
    }
    bf16x8 a0 = *(bf16x8*)&v0, a1 = *(bf16x8*)&v1;

    f32x4 oc[4];
    conv_core(a0, a1, (const bf16x8*)w1p, b1, (const bf16x8*)w2p, tls[wv], c, q, l, oc);

#pragma unroll
    for (int t = 0; t < 4; t++) {
        float bb = b2[16 * t + c];
#pragma unroll
        for (int rg = 0; rg < 4; rg++) {
            int row = rbase + 4 * q + rg;
            if (row < NN) {
                float v = oc[t][rg] + bb;
                if constexpr (ADD) v += hprev[(size_t)row * 64 + 16 * t + c];
                out[(size_t)row * 64 + 16 * t + c] = v;
                if constexpr (WB) {
                    float o = __shfl_xor(v, 1);
                    if ((c & 1) == 0)
                        hb[(size_t)row * 32 + 8 * t + (c >> 1)] = bf2(v, o);
                }
            }
        }
    }
}

// ---------------- dual conv: outa = conv_a(m); outb = hprev + conv_b(m) (+bf16 WB) ----------------

__global__ __launch_bounds__(256) void conv2_k(const unsigned int* __restrict__ mb,
                                               const short* __restrict__ wa1,
                                               const float* __restrict__ ba1,
                                               const short* __restrict__ wa2,
                                               const float* __restrict__ ba2,
                                               const short* __restrict__ wb1,
                                               const float* __restrict__ bb1,
                                               const short* __restrict__ wb2,
                                               const float* __restrict__ bb2,
                                               const float* __restrict__ hprev,
                                               float* __restrict__ outa,
                                               float* __restrict__ outb,
                                               unsigned int* __restrict__ hb) {
    __shared__ short tls[4][16 * 72];
    int wv = threadIdx.x >> 6, l = threadIdx.x & 63;
    int c = l & 15, q = l >> 4;
    int rbase = blockIdx.x * 64 + wv * 16;

    int ar = rbase + c;
    bool aok = ar < NN;
    uint4 v0 = make_uint4(0, 0, 0, 0), v1 = v0;
    if (aok) {
        const uint4* mp = (const uint4*)(mb + (size_t)ar * 32);
        v0 = mp[q];
        v1 = mp[4 + q];
    }
    bf16x8 a0 = *(bf16x8*)&v0, a1 = *(bf16x8*)&v1;

    f32x4 oc[4];
    conv_core(a0, a1, (const bf16x8*)wa1, ba1, (const bf16x8*)wa2, tls[wv], c, q, l, oc);
#pragma unroll
    for (int t = 0; t < 4; t++) {
        float bb = ba2[16 * t + c];
#pragma unroll
        for (int rg = 0; rg < 4; rg++) {
            int row = rbase + 4 * q + rg;
            if (row < NN)
                outa[(size_t)row * 64 + 16 * t + c] = oc[t][rg] + bb;
        }
    }
    __syncthreads();  // tls reuse

    conv_core(a0, a1, (const bf16x8*)wb1, bb1, (const bf16x8*)wb2, tls[wv], c, q, l, oc);
#pragma unroll
    for (int t = 0; t < 4; t++) {
        float bb = bb2[16 * t + c];
#pragma unroll
        for (int rg = 0; rg < 4; rg++) {
            int row = rbase + 4 * q + rg;
            if (row < NN) {
                float v = oc[t][rg] + bb + hprev[(size_t)row * 64 + 16 * t + c];
                outb[(size_t)row * 64 + 16 * t + c] = v;
                float o = __shfl_xor(v, 1);
                if ((c & 1) == 0)
                    hb[(size_t)row * 32 + 8 * t + (c >> 1)] = bf2(v, o);
            }
        }
    }
}

// ---------------- MFMA input linear: h0 = x @ lin_W + lin_b (+ bf16 copy) ----------------

__global__ __launch_bounds__(256) void linm_k(const float* __restrict__ x,
                                              const short* __restrict__ wp,
                                              const float* __restrict__ b,
                                              float* __restrict__ h0,
                                              unsigned int* __restrict__ hb) {
    int wv = threadIdx.x >> 6, l = threadIdx.x & 63;
    int c = l & 15, q = l >> 4;
    int rbase = blockIdx.x * 64 + wv * 16;
    int ar = rbase + c;
    bool aok = ar < NN;

    bf16x8 af[4];
#pragma unroll
    for (int s = 0; s < 4; s++) {
        float4 p0 = make_float4(0, 0, 0, 0), p1 = p0;
        if (aok) {
            const float4* xp = (const float4*)(x + (size_t)ar * FIN + 32 * s + 8 * q);
            p0 = xp[0];
            p1 = xp[1];
        }
        bf16x8 t;
        t[0] = (short)bfr(p0.x); t[1] = (short)bfr(p0.y);
        t[2] = (short)bfr(p0.z); t[3] = (short)bfr(p0.w);
        t[4] = (short)bfr(p1.x); t[5] = (short)bfr(p1.y);
        t[6] = (short)bfr(p1.z); t[7] = (short)bfr(p1.w);
        af[s] = t;
    }

    const bf16x8* wf = (const bf16x8*)wp;
    f32x4 acc[4];
#pragma unroll
    for (int t = 0; t < 4; t++) acc[t] = (f32x4){0.f, 0.f, 0.f, 0.f};
#pragma unroll
    for (int t = 0; t < 4; t++)
#pragma unroll
        for (int s = 0; s < 4; s++)
            acc[t] = MFMA(af[s], wf[(t * 4 + s) * 64 + l], acc[t]);

#pragma unroll
    for (int t = 0; t < 4; t++) {
        float bb = b[16 * t + c];
#pragma unroll
        for (int rg = 0; rg < 4; rg++) {
            int row = rbase + 4 * q + rg;
            if (row < NN) {
                float v = acc[t][rg] + bb;
                h0[(size_t)row * 64 + 16 * t + c] = v;
                float o = __shfl_xor(v, 1);
                if ((c & 1) == 0)
                    hb[(size_t)row * 32 + 8 * t + (c >> 1)] = bf2(v, o);
            }
        }
    }
}

// ---------------- launch ----------------

extern "C" void kernel_launch(void* const* d_in, const int* in_sizes, int n_in,
                              void* d_out, int out_size, void* d_ws, size_t ws_size,
                              hipStream_t stream) {
    (void)in_sizes; (void)n_in; (void)out_size; (void)ws_size;

    const float* x    = (const float*)d_in[0];
    const int*   ei   = (const int*)d_in[1];
    const float* attr = (const float*)d_in[2];
    const float* linW = (const float*)d_in[3];
    const float* linb = (const float*)d_in[4];
    const float* W1   = (const float*)d_in[5];
    const float* b1   = (const float*)d_in[6];
    const float* W2   = (const float*)d_in[7];
    const float* b2   = (const float*)d_in[8];
    float* out = (float*)d_out;

    // workspace (16B alignment at each boundary)
    float*        h0     = (float*)d_ws;                          // NN*64 f32 (12.8MB)
    unsigned int* mb     = (unsigned int*)(h0 + (size_t)NN * HD); // NN*32 (bf16 m)
    unsigned int* hb     = mb + (size_t)NN * 32;                  // NN*32 (bf16 h)
    int2*         cedge  = (int2*)(hb + (size_t)NN * 32);         // NE (node-sorted)
    short*        prep   = (short*)(cedge + NE);                  // 32768 shorts
    int*          off    = (int*)(prep + 32768);                  // NN+1
    int*          gcur   = off + NN + 1;                          // 256 (bin counts)
    int2*         tedge  = (int2*)h0;  // ALIAS: 196*CAP*8B = 12.64MB <= 12.8MB; h0 dead until linm_k

    const int* src = ei;
    const int* dst = ei + NE;

    float* scats = out;
    float* outs  = out + (size_t)SL * NN * HD;

    const size_t NH = (size_t)NN * HD;
    const int WB_ = (NN * 64) / 256;

    const short* w1p0 = prep;            // layer i: prep + i*8192
    const short* w2p0 = prep + 4096;
    const short* linp = prep + 24576;

    // CSR build: zero -> strided binpass (counts in gcur) -> fused sort+wprep
    zero_k<<<1, 256, 0, stream>>>(gcur);
    binpass_k<<<782, 256, 0, stream>>>(src, dst, attr, gcur, tedge);
    sortprep_k<<<NBIN + 128, 256, 0, stream>>>(gcur, tedge, cedge, off,
                                               W1, W2, linW, prep);

    // h0 = x @ lin_W + lin_b (+ bf16 into hb)
    linm_k<<<GBM, 256, 0, stream>>>(x, linp, linb, h0, hb);

    // layer 0
    scatter_k<<<WB_, 256, 0, stream>>>((const uint4*)hb, off, cedge, (uint4*)mb);
    convm_k<true, true><<<GBM, 256, 0, stream>>>(mb, w1p0, b1, w2p0, b2, h0, outs, hb);

    // scatter(outs0): scats0 (W0) + outs1 (W1) fused
    scatter_k<<<WB_, 256, 0, stream>>>((const uint4*)hb, off, cedge, (uint4*)mb);
    conv2_k<<<GBM, 256, 0, stream>>>(mb, w1p0, b1, w2p0, b2,
                                     w1p0 + 8192, b1 + 64, w2p0 + 8192, b2 + 64,
                                     outs, scats, outs + NH, hb);

    // scatter(outs1): scats1 (W1) + outs2 (W2) fused
    scatter_k<<<WB_, 256, 0, stream>>>((const uint4*)hb, off, cedge, (uint4*)mb);
    conv2_k<<<GBM, 256, 0, stream>>>(mb, w1p0 + 8192, b1 + 64, w2p0 + 8192, b2 + 64,
                                     w1p0 + 16384, b1 + 128, w2p0 + 16384, b2 + 128,
                                     outs + NH, scats + NH, outs + 2 * NH, hb);

    // scatter(outs2): scats2 (W2)
    scatter_k<<<WB_, 256, 0, stream>>>((const uint4*)hb, off, cedge, (uint4*)mb);
    convm_k<false, false><<<GBM, 256, 0, stream>>>(mb, w1p0 + 16384, b1 + 128,
                                                   w2p0 + 16384, b2 + 128,
                                                   nullptr, scats + 2 * NH, nullptr);
}

// Round 16
// 205.342 us; speedup vs baseline: 1.2554x; 1.0393x over previous
//
#include <hip/hip_runtime.h>

#define NN 50000
#define NE 800000
#define FIN 128
#define HD 64
#define SL 3
#define GBM 782    // ceil(NN/64) row-tiles for MFMA kernels
#define NBIN 196   // ceil(NN/256) dst bins
#define BSH 8      // 256 nodes per bin
#define CAP 8064   // per-bin tedge capacity (mean 4082, ~62 sigma headroom)

typedef __attribute__((ext_vector_type(8))) short bf16x8;
typedef __attribute__((ext_vector_type(4))) float f32x4;
#define MFMA(A, B, C) __builtin_amdgcn_mfma_f32_16x16x32_bf16(A, B, C, 0, 0, 0)

// ---------------- bf16 pack helpers (RNE) ----------------

__device__ __forceinline__ unsigned int bfr(float x) {
    unsigned int u = __float_as_uint(x);
    return (u + 0x7fffu + ((u >> 16) & 1u)) >> 16;
}
__device__ __forceinline__ unsigned int bf2(float lo, float hi) {
    return bfr(lo) | (bfr(hi) << 16);
}

// ---------------- CSR build ----------------

// replaces hipMemsetAsync (captured fillBufferAligned costs ~47 us/replay)
__global__ void zero_k(int* __restrict__ g) {
    if (threadIdx.x < NBIN) g[threadIdx.x] = 0;
}

// partition edges into per-bin STRIDED runs (tedge[b*CAP + ...]); gcur counts.
// packed: src (16b) | (dst & 255) << 16.  4096 edges/block x 196 blocks (R11 config).
__global__ __launch_bounds__(256) void binpass_k(const int* __restrict__ src,
                                                 const int* __restrict__ dst,
                                                 const float* __restrict__ attr,
                                                 int* __restrict__ gcur,
                                                 int2* __restrict__ tedge) {
    __shared__ int cnt_lds[256], runbase[256], lcur[256];
    int t = threadIdx.x;
    cnt_lds[t] = 0;
    lcur[t] = 0;
    __syncthreads();
    int base = blockIdx.x * 4096;
    for (int i = t; i < 4096; i += 256) {
        int e = base + i;
        if (e < NE) atomicAdd(&cnt_lds[dst[e] >> BSH], 1);
    }
    __syncthreads();
    if (t < NBIN && cnt_lds[t]) runbase[t] = atomicAdd(&gcur[t], cnt_lds[t]);
    __syncthreads();
    for (int i = t; i < 4096; i += 256) {
        int e = base + i;
        if (e < NE) {
            int d = dst[e];
            int b = d >> BSH;
            int r = atomicAdd(&lcur[b], 1);
            tedge[(size_t)b * CAP + runbase[b] + r] =
                make_int2(src[e] | ((d & 255) << 16), __float_as_int(attr[e]));
        }
    }
}

// blocks [0,NBIN): per-bin counting sort; blocks [NBIN,NBIN+128): weight prep.
__global__ __launch_bounds__(256) void sortprep_k(const int* __restrict__ gcur,
                                                  const int2* __restrict__ tedge,
                                                  int2* __restrict__ cedge,
                                                  int* __restrict__ off,
                                                  const float* __restrict__ W1,
                                                  const float* __restrict__ W2,
                                                  const float* __restrict__ linW,
                                                  short* __restrict__ prep) {
    int t = threadIdx.x;
    if (blockIdx.x >= NBIN) {
        int i = (blockIdx.x - NBIN) * 256 + t;
        if (i < 24576) {
            int mat = i >> 12;
            int o = i & 4095;
            int j = o & 7, l = (o >> 3) & 63, s = (o >> 9) & 1, tt = o >> 10;
            int k = 32 * s + 8 * (l >> 4) + j;
            int n = 16 * tt + (l & 15);
            const float* Wsrc = (mat & 1) ? W2 : W1;
            prep[i] = (short)bfr(Wsrc[(mat >> 1) * 4096 + k * 64 + n]);
        } else if (i < 32768) {
            int o = i - 24576;
            int j = o & 7, l = (o >> 3) & 63, s = (o >> 9) & 3, tt = o >> 11;
            int k = 32 * s + 8 * (l >> 4) + j;
            int n = 16 * tt + (l & 15);
            prep[i] = (short)bfr(linW[k * 64 + n]);
        }
        return;
    }
    __shared__ int sh[256], cnt[256], lofs[256], lcur[256];
    int b = blockIdx.x;
    int v = (t < NBIN) ? gcur[t] : 0;
    sh[t] = v;
    __syncthreads();
    for (int d = 1; d < 256; d <<= 1) {
        int u = (t >= d) ? sh[t - d] : 0;
        __syncthreads();
        sh[t] += u;
        __syncthreads();
    }
    int s = (b == 0) ? 0 : sh[b - 1];       // binoff[b]
    int n_in_bin = sh[b] - s;
    if (b == NBIN - 1 && t == 0) off[NN] = sh[NBIN - 1];  // == NE

    const int2* tb = tedge + (size_t)b * CAP;
    cnt[t] = 0;
    __syncthreads();
    for (int i = t; i < n_in_bin; i += 256)
        atomicAdd(&cnt[((unsigned)tb[i].x >> 16) & 255], 1);
    __syncthreads();
    int cv = cnt[t];
    lofs[t] = cv;
    __syncthreads();
    for (int d = 1; d < 256; d <<= 1) {
        int u = (t >= d) ? lofs[t - d] : 0;
        __syncthreads();
        lofs[t] += u;
        __syncthreads();
    }
    int ex = lofs[t] - cv;  // exclusive prefix within bin
    int node = (b << BSH) + t;
    if (node < NN) off[node] = s + ex;
    lcur[t] = ex;
    __syncthreads();
    for (int i = t; i < n_in_bin; i += 256) {
        int2 ed = tb[i];
        int dl = ((unsigned)ed.x >> 16) & 255;
        int p = s + atomicAdd(&lcur[dl], 1);
        cedge[p] = make_int2(ed.x & 0xffff, ed.y);
    }
}

// ---------------- scatter: mb[n] = bf16( sum attr[e] * hb[src[e]] ) ----------------
// wave per dst node; 8 lanes per edge, shfl-xor tree reduce. No atomics.
// (Best measured structure; R9 fusion and R13 feature-split both regressed.)

__global__ __launch_bounds__(256) void scatter_k(const uint4* __restrict__ hb4,
                                                 const int* __restrict__ off,
                                                 const int2* __restrict__ cedge,
                                                 uint4* __restrict__ mb4) {
    int w    = (blockIdx.x * blockDim.x + threadIdx.x) >> 6;
    int lane = threadIdx.x & 63;
    if (w >= NN) return;
    int g = lane >> 3;
    int f = lane & 7;
    int s = off[w], e = off[w + 1];
    float a0 = 0.f, a1 = 0.f, a2 = 0.f, a3 = 0.f;
    float a4 = 0.f, a5 = 0.f, a6 = 0.f, a7 = 0.f;
    for (int i = s + g; i < e; i += 8) {
        int2 ed = cedge[i];
        uint4 hv = hb4[(size_t)ed.x * 8 + f];
        float a = __int_as_float(ed.y);
        a0 += a * __uint_as_float(hv.x << 16);
        a1 += a * __uint_as_float(hv.x & 0xffff0000u);
        a2 += a * __uint_as_float(hv.y << 16);
        a3 += a * __uint_as_float(hv.y & 0xffff0000u);
        a4 += a * __uint_as_float(hv.z << 16);
        a5 += a * __uint_as_float(hv.z & 0xffff0000u);
        a6 += a * __uint_as_float(hv.w << 16);
        a7 += a * __uint_as_float(hv.w & 0xffff0000u);
    }
#pragma unroll
    for (int msk = 8; msk <= 32; msk <<= 1) {
        a0 += __shfl_xor(a0, msk);
        a1 += __shfl_xor(a1, msk);
        a2 += __shfl_xor(a2, msk);
        a3 += __shfl_xor(a3, msk);
        a4 += __shfl_xor(a4, msk);
        a5 += __shfl_xor(a5, msk);
        a6 += __shfl_xor(a6, msk);
        a7 += __shfl_xor(a7, msk);
    }
    if (g == 0) {
        uint4 o;
        o.x = bf2(a0, a1);
        o.y = bf2(a2, a3);
        o.z = bf2(a4, a5);
        o.w = bf2(a6, a7);
        mb4[(size_t)w * 8 + f] = o;
    }
}

// ---------------- MFMA conv core (one weight set) ----------------

__device__ __forceinline__ void conv_core(bf16x8 a0, bf16x8 a1,
                                          const bf16x8* __restrict__ w1f,
                                          const float* __restrict__ b1,
                                          const bf16x8* __restrict__ w2f,
                                          short* tw, int c, int q, int l,
                                          f32x4 oc[4]) {
    f32x4 acc[4];
#pragma unroll
    for (int t = 0; t < 4; t++) acc[t] = (f32x4){0.f, 0.f, 0.f, 0.f};
#pragma unroll
    for (int t = 0; t < 4; t++) {
        acc[t] = MFMA(a0, w1f[(t * 2 + 0) * 64 + l], acc[t]);
        acc[t] = MFMA(a1, w1f[(t * 2 + 1) * 64 + l], acc[t]);
    }
#pragma unroll
    for (int t = 0; t < 4; t++) {
        float bb = b1[16 * t + c];
#pragma unroll
        for (int rg = 0; rg < 4; rg++) {
            float v = fmaxf(acc[t][rg] + bb, 0.f);
            tw[(4 * q + rg) * 72 + 16 * t + c] = (short)bfr(v);
        }
    }
    __syncthreads();
    bf16x8 ta0 = *(const bf16x8*)&tw[c * 72 + 8 * q];
    bf16x8 ta1 = *(const bf16x8*)&tw[c * 72 + 32 + 8 * q];
#pragma unroll
    for (int t = 0; t < 4; t++) oc[t] = (f32x4){0.f, 0.f, 0.f, 0.f};
#pragma unroll
    for (int t = 0; t < 4; t++) {
        oc[t] = MFMA(ta0, w2f[(t * 2 + 0) * 64 + l], oc[t]);
        oc[t] = MFMA(ta1, w2f[(t * 2 + 1) * 64 + l], oc[t]);
    }
}

// ---------------- single conv: out = [hprev +] relu(m@W1+b1)@W2+b2 ----------------

template <bool ADD, bool WB>
__global__ __launch_bounds__(256) void convm_k(const unsigned int* __restrict__ mb,
                                               const short* __restrict__ w1p,
                                               const float* __restrict__ b1,
                                               const short* __restrict__ w2p,
                                               const float* __restrict__ b2,
                                               const float* __restrict__ hprev,
                                               float* __restrict__ out,
                                               unsigned int* __restrict__ hb) {
    __shared__ short tls[4][16 * 72];
    int wv = threadIdx.x >> 6, l = threadIdx.x & 63;
    int c = l & 15, q = l >> 4;
    int rbase = blockIdx.x * 64 + wv * 16;

    int ar = rbase + c;
    bool aok = ar < NN;
    uint4 v0 = make_uint4(0, 0, 0, 0), v1 = v0;
    if (aok) {
        const uint4* mp = (const uint4*)(mb + (size_t)ar * 32);
        v0 = mp[q];
        v1 = mp[4 + q];
    }
    bf16x8 a0 = *(bf16x8*)&v0, a1 = *(bf16x8*)&v1;

    f32x4 oc[4];
    conv_core(a0, a1, (const bf16x8*)w1p, b1, (const bf16x8*)w2p, tls[wv], c, q, l, oc);

#pragma unroll
    for (int t = 0; t < 4; t++) {
        float bb = b2[16 * t + c];
#pragma unroll
        for (int rg = 0; rg < 4; rg++) {
            int row = rbase + 4 * q + rg;
            if (row < NN) {
                float v = oc[t][rg] + bb;
                if constexpr (ADD) v += hprev[(size_t)row * 64 + 16 * t + c];
                out[(size_t)row * 64 + 16 * t + c] = v;
                if constexpr (WB) {
                    float o = __shfl_xor(v, 1);
                    if ((c & 1) == 0)
                        hb[(size_t)row * 32 + 8 * t + (c >> 1)] = bf2(v, o);
                }
            }
        }
    }
}

// ---------------- dual conv: outa = conv_a(m); outb = hprev + conv_b(m) (+bf16 WB) ----------------

__global__ __launch_bounds__(256) void conv2_k(const unsigned int* __restrict__ mb,
                                               const short* __restrict__ wa1,
                                               const float* __restrict__ ba1,
                                               const short* __restrict__ wa2,
                                               const float* __restrict__ ba2,
                                               const short* __restrict__ wb1,
                                               const float* __restrict__ bb1,
                                               const short* __restrict__ wb2,
                                               const float* __restrict__ bb2,
                                               const float* __restrict__ hprev,
                                               float* __restrict__ outa,
                                               float* __restrict__ outb,
                                               unsigned int* __restrict__ hb) {
    __shared__ short tls[4][16 * 72];
    int wv = threadIdx.x >> 6, l = threadIdx.x & 63;
    int c = l & 15, q = l >> 4;
    int rbase = blockIdx.x * 64 + wv * 16;

    int ar = rbase + c;
    bool aok = ar < NN;
    uint4 v0 = make_uint4(0, 0, 0, 0), v1 = v0;
    if (aok) {
        const uint4* mp = (const uint4*)(mb + (size_t)ar * 32);
        v0 = mp[q];
        v1 = mp[4 + q];
    }
    bf16x8 a0 = *(bf16x8*)&v0, a1 = *(bf16x8*)&v1;

    f32x4 oc[4];
    conv_core(a0, a1, (const bf16x8*)wa1, ba1, (const bf16x8*)wa2, tls[wv], c, q, l, oc);
#pragma unroll
    for (int t = 0; t < 4; t++) {
        float bb = ba2[16 * t + c];
#pragma unroll
        for (int rg = 0; rg < 4; rg++) {
            int row = rbase + 4 * q + rg;
            if (row < NN)
                outa[(size_t)row * 64 + 16 * t + c] = oc[t][rg] + bb;
        }
    }
    __syncthreads();  // tls reuse

    conv_core(a0, a1, (const bf16x8*)wb1, bb1, (const bf16x8*)wb2, tls[wv], c, q, l, oc);
#pragma unroll
    for (int t = 0; t < 4; t++) {
        float bb = bb2[16 * t + c];
#pragma unroll
        for (int rg = 0; rg < 4; rg++) {
            int row = rbase + 4 * q + rg;
            if (row < NN) {
                float v = oc[t][rg] + bb + hprev[(size_t)row * 64 + 16 * t + c];
                outb[(size_t)row * 64 + 16 * t + c] = v;
                float o = __shfl_xor(v, 1);
                if ((c & 1) == 0)
                    hb[(size_t)row * 32 + 8 * t + (c >> 1)] = bf2(v, o);
            }
        }
    }
}

// ---------------- MFMA input linear: h0 = x @ lin_W + lin_b (+ bf16 copy) ----------------

__global__ __launch_bounds__(256) void linm_k(const float* __restrict__ x,
                                              const short* __restrict__ wp,
                                              const float* __restrict__ b,
                                              float* __restrict__ h0,
                                              unsigned int* __restrict__ hb) {
    int wv = threadIdx.x >> 6, l = threadIdx.x & 63;
    int c = l & 15, q = l >> 4;
    int rbase = blockIdx.x * 64 + wv * 16;
    int ar = rbase + c;
    bool aok = ar < NN;

    bf16x8 af[4];
#pragma unroll
    for (int s = 0; s < 4; s++) {
        float4 p0 = make_float4(0, 0, 0, 0), p1 = p0;
        if (aok) {
            const float4* xp = (const float4*)(x + (size_t)ar * FIN + 32 * s + 8 * q);
            p0 = xp[0];
            p1 = xp[1];
        }
        bf16x8 t;
        t[0] = (short)bfr(p0.x); t[1] = (short)bfr(p0.y);
        t[2] = (short)bfr(p0.z); t[3] = (short)bfr(p0.w);
        t[4] = (short)bfr(p1.x); t[5] = (short)bfr(p1.y);
        t[6] = (short)bfr(p1.z); t[7] = (short)bfr(p1.w);
        af[s] = t;
    }

    const bf16x8* wf = (const bf16x8*)wp;
    f32x4 acc[4];
#pragma unroll
    for (int t = 0; t < 4; t++) acc[t] = (f32x4){0.f, 0.f, 0.f, 0.f};
#pragma unroll
    for (int t = 0; t < 4; t++)
#pragma unroll
        for (int s = 0; s < 4; s++)
            acc[t] = MFMA(af[s], wf[(t * 4 + s) * 64 + l], acc[t]);

#pragma unroll
    for (int t = 0; t < 4; t++) {
        float bb = b[16 * t + c];
#pragma unroll
        for (int rg = 0; rg < 4; rg++) {
            int row = rbase + 4 * q + rg;
            if (row < NN) {
                float v = acc[t][rg] + bb;
                h0[(size_t)row * 64 + 16 * t + c] = v;
                float o = __shfl_xor(v, 1);
                if ((c & 1) == 0)
                    hb[(size_t)row * 32 + 8 * t + (c >> 1)] = bf2(v, o);
            }
        }
    }
}

// ---------------- launch ----------------

extern "C" void kernel_launch(void* const* d_in, const int* in_sizes, int n_in,
                              void* d_out, int out_size, void* d_ws, size_t ws_size,
                              hipStream_t stream) {
    (void)in_sizes; (void)n_in; (void)out_size; (void)ws_size;

    const float* x    = (const float*)d_in[0];
    const int*   ei   = (const int*)d_in[1];
    const float* attr = (const float*)d_in[2];
    const float* linW = (const float*)d_in[3];
    const float* linb = (const float*)d_in[4];
    const float* W1   = (const float*)d_in[5];
    const float* b1   = (const float*)d_in[6];
    const float* W2   = (const float*)d_in[7];
    const float* b2   = (const float*)d_in[8];
    float* out = (float*)d_out;

    // workspace (16B alignment at each boundary)
    float*        h0     = (float*)d_ws;                          // NN*64 f32 (12.8MB)
    unsigned int* mb     = (unsigned int*)(h0 + (size_t)NN * HD); // NN*32 (bf16 m)
    unsigned int* hb     = mb + (size_t)NN * 32;                  // NN*32 (bf16 h)
    int2*         cedge  = (int2*)(hb + (size_t)NN * 32);         // NE (node-sorted)
    short*        prep   = (short*)(cedge + NE);                  // 32768 shorts
    int*          off    = (int*)(prep + 32768);                  // NN+1
    int*          gcur   = off + NN + 1;                          // 256 (bin counts)
    int2*         tedge  = (int2*)h0;  // ALIAS: 196*CAP*8B = 12.64MB <= 12.8MB; h0 dead until linm_k

    const int* src = ei;
    const int* dst = ei + NE;

    float* scats = out;
    float* outs  = out + (size_t)SL * NN * HD;

    const size_t NH = (size_t)NN * HD;
    const int WB_ = (NN * 64) / 256;

    const short* w1p0 = prep;            // layer i: prep + i*8192
    const short* w2p0 = prep + 4096;
    const short* linp = prep + 24576;

    // CSR build: zero -> strided binpass (counts in gcur) -> fused sort+wprep
    zero_k<<<1, 256, 0, stream>>>(gcur);
    binpass_k<<<196, 256, 0, stream>>>(src, dst, attr, gcur, tedge);
    sortprep_k<<<NBIN + 128, 256, 0, stream>>>(gcur, tedge, cedge, off,
                                               W1, W2, linW, prep);

    // h0 = x @ lin_W + lin_b (+ bf16 into hb)
    linm_k<<<GBM, 256, 0, stream>>>(x, linp, linb, h0, hb);

    // layer 0
    scatter_k<<<WB_, 256, 0, stream>>>((const uint4*)hb, off, cedge, (uint4*)mb);
    convm_k<true, true><<<GBM, 256, 0, stream>>>(mb, w1p0, b1, w2p0, b2, h0, outs, hb);

    // scatter(outs0): scats0 (W0) + outs1 (W1) fused
    scatter_k<<<WB_, 256, 0, stream>>>((const uint4*)hb, off, cedge, (uint4*)mb);
    conv2_k<<<GBM, 256, 0, stream>>>(mb, w1p0, b1, w2p0, b2,
                                     w1p0 + 8192, b1 + 64, w2p0 + 8192, b2 + 64,
                                     outs, scats, outs + NH, hb);

    // scatter(outs1): scats1 (W1) + outs2 (W2) fused
    scatter_k<<<WB_, 256, 0, stream>>>((const uint4*)hb, off, cedge, (uint4*)mb);
    conv2_k<<<GBM, 256, 0, stream>>>(mb, w1p0 + 8192, b1 + 64, w2p0 + 8192, b2 + 64,
                                     w1p0 + 16384, b1 + 128, w2p0 + 16384, b2 + 128,
                                     outs + NH, scats + NH, outs + 2 * NH, hb);

    // scatter(outs2): scats2 (W2)
    scatter_k<<<WB_, 256, 0, stream>>>((const uint4*)hb, off, cedge, (uint4*)mb);
    convm_k<false, false><<<GBM, 256, 0, stream>>>(mb, w1p0 + 16384, b1 + 128,
                                                   w2p0 + 16384, b2 + 128,
                                                   nullptr, scats + 2 * NH, nullptr);
}